// Round 1
// baseline (1342.370 us; speedup 1.0000x reference)
//
#include <hip/hip_runtime.h>
#include <math.h>

#define N_IMG 128
#define EPS 1e-5f

// ---------- helpers ----------
__device__ __forceinline__ float gelu_f(float x) {
    return 0.5f * x * (1.0f + erff(x * 0.70710678118654752f));
}

__device__ __forceinline__ float wave_sum(float v) {
    #pragma unroll
    for (int m = 1; m < 64; m <<= 1) v += __shfl_xor(v, m);
    return v;
}

__device__ __forceinline__ void fma4(float4& acc, float s, const float4& v) {
    acc.x += s * v.x; acc.y += s * v.y; acc.z += s * v.z; acc.w += s * v.w;
}

// ---------- positional-embedding table: pe[197][64] ----------
__global__ void k_posemb(float* __restrict__ pe) {
    int idx = blockIdx.x * 256 + threadIdx.x;
    if (idx >= 197 * 64) return;
    int i = idx >> 6, j = idx & 63;
    int jj = j & ~1;
    float inv = powf(10000.0f, (float)jj / 64.0f);
    float a = (float)i / inv;
    pe[idx] = (j & 1) ? cosf(a) : sinf(a);
}

// ---------- patch embed: tokens = patchify(img) @ lm_W + lm_b + pe[1+p] ----------
// M=25088 rows, K=1024, N=64. Tile 64x64, K-chunks of 32 (one patch row).
__global__ __launch_bounds__(256) void k_patch(
    const float* __restrict__ img, const float* __restrict__ W,
    const float* __restrict__ bias, const float* __restrict__ pe,
    float* __restrict__ x)
{
    __shared__ float As[64 * 36];   // pitch 36 floats (16B aligned rows, conflict-free)
    __shared__ float Bs[32 * 64];
    int tid = threadIdx.x;
    int tx = tid & 15, ty = tid >> 4;
    int m0 = blockIdx.x * 64;

    // A loader: thread -> row ra (0..63), 8 floats at ca
    int ra = tid >> 2, ca = (tid & 3) * 8;
    int rowa = m0 + ra;
    int na = rowa / 196, pa = rowa - na * 196;
    const float* abase = img + (size_t)na * 200704 + (pa / 14) * (32 * 448) + (pa % 14) * 32 + ca;

    // B loader: thread -> k-row kr (0..31), 8 floats at cb
    int kr = tid >> 3, cb = (tid & 7) * 8;

    float4 acc[4];
    #pragma unroll
    for (int i = 0; i < 4; ++i) acc[i] = make_float4(0.f, 0.f, 0.f, 0.f);

    for (int kc = 0; kc < 32; ++kc) {
        float4 a0 = *(const float4*)(abase + kc * 448);
        float4 a1 = *(const float4*)(abase + kc * 448 + 4);
        const float* wp = W + (size_t)(kc * 32 + kr) * 64 + cb;
        float4 b0 = *(const float4*)(wp);
        float4 b1 = *(const float4*)(wp + 4);
        __syncthreads();
        *(float4*)&As[ra * 36 + ca]     = a0;
        *(float4*)&As[ra * 36 + ca + 4] = a1;
        *(float4*)&Bs[kr * 64 + cb]     = b0;
        *(float4*)&Bs[kr * 64 + cb + 4] = b1;
        __syncthreads();
        #pragma unroll
        for (int k4 = 0; k4 < 8; ++k4) {
            float4 a[4], b[4];
            #pragma unroll
            for (int i = 0; i < 4; ++i) a[i] = *(float4*)&As[(ty + 16 * i) * 36 + k4 * 4];
            #pragma unroll
            for (int kk = 0; kk < 4; ++kk) b[kk] = *(float4*)&Bs[(k4 * 4 + kk) * 64 + tx * 4];
            #pragma unroll
            for (int i = 0; i < 4; ++i) {
                fma4(acc[i], a[i].x, b[0]);
                fma4(acc[i], a[i].y, b[1]);
                fma4(acc[i], a[i].z, b[2]);
                fma4(acc[i], a[i].w, b[3]);
            }
        }
    }
    int col = tx * 4;
    float4 bb = *(const float4*)(bias + col);
    #pragma unroll
    for (int i = 0; i < 4; ++i) {
        int row = m0 + ty + 16 * i;
        int n = row / 196, p = row - n * 196;
        float4 pv = *(const float4*)(pe + (size_t)(1 + p) * 64 + col);
        float4 o;
        o.x = acc[i].x + bb.x + pv.x;
        o.y = acc[i].y + bb.y + pv.y;
        o.z = acc[i].z + bb.z + pv.z;
        o.w = acc[i].w + bb.w + pv.w;
        *(float4*)&x[((size_t)(n * 197 + 1 + p)) * 64 + col] = o;
    }
}

// ---------- class-token row ----------
__global__ void k_cls(const float* __restrict__ cls, const float* __restrict__ pe,
                      float* __restrict__ x) {
    int idx = blockIdx.x * 256 + threadIdx.x;
    if (idx >= 128 * 64) return;
    int n = idx >> 6, j = idx & 63;
    x[(size_t)n * 197 * 64 + j] = cls[j] + pe[j];
}

// ---------- LN1 + QKV projection ----------
// wave per row; q/k/v layout [n][h][s][16]
__global__ __launch_bounds__(256) void k_ln_qkv(
    const float* __restrict__ x, const float* __restrict__ g, const float* __restrict__ bta,
    const float* __restrict__ Wq, const float* __restrict__ bq,
    const float* __restrict__ Wk, const float* __restrict__ bk,
    const float* __restrict__ Wv, const float* __restrict__ bv,
    float* __restrict__ q, float* __restrict__ k, float* __restrict__ v, int S)
{
    __shared__ float z[4][64];
    int tid = threadIdx.x, w = tid >> 6, l = tid & 63;
    int row = blockIdx.x * 4 + w;
    if (row >= N_IMG * S) return;
    float xv = x[(size_t)row * 64 + l];
    float m = wave_sum(xv) * (1.0f / 64.0f);
    float t = xv - m;
    float var = wave_sum(t * t) * (1.0f / 64.0f);
    float zv = t * rsqrtf(var + EPS) * g[l] + bta[l];
    z[w][l] = zv;
    int h = l >> 4, e = l & 15;
    const float* zh = &z[w][h * 16];
    const float* wq = Wq + h * 256 + e;
    const float* wk = Wk + h * 256 + e;
    const float* wv = Wv + h * 256 + e;
    float aq = bq[l], ak = bk[l], av = bv[l];
    #pragma unroll
    for (int d = 0; d < 16; ++d) {
        float zd = zh[d];
        aq += zd * wq[d * 16];
        ak += zd * wk[d * 16];
        av += zd * wv[d * 16];
    }
    int n = row / S, s = row - n * S;
    size_t o = ((size_t)((n * 4 + h) * S + s)) * 16 + e;
    q[o] = aq; k[o] = ak; v[o] = av;
}

// ---------- attention: lane-per-query online softmax, K/V via scalar loads ----------
// h = x + concat_heads(softmax(QK^T/4) V); grid = n*4+h blocks of 256 threads
__global__ __launch_bounds__(256) void k_attn(
    const float* __restrict__ q, const float* __restrict__ k, const float* __restrict__ v,
    const float* __restrict__ x, float* __restrict__ hout, int S)
{
    int h = blockIdx.x & 3, n = blockIdx.x >> 2;
    int tid = threadIdx.x;
    int s = tid < S ? tid : S - 1;
    const float* qrow = q + ((size_t)((n * 4 + h) * S + s)) * 16;
    float qr[16];
    #pragma unroll
    for (int e = 0; e < 16; ++e) qr[e] = qrow[e] * 0.25f;   // fold 1/sqrt(16)
    const float* kp = k + ((size_t)(n * 4 + h)) * S * 16;
    const float* vp = v + ((size_t)(n * 4 + h)) * S * 16;
    float mx = -1e30f, l = 0.0f;
    float o[16];
    #pragma unroll
    for (int e = 0; e < 16; ++e) o[e] = 0.0f;
    for (int j = 0; j < S; ++j) {
        float sc = 0.0f;
        #pragma unroll
        for (int e = 0; e < 16; ++e) sc += qr[e] * kp[e];   // kp uniform -> s_load
        if (__any(sc > mx)) {
            float mn = fmaxf(mx, sc);
            float alpha = __expf(mx - mn);
            float p = __expf(sc - mn);
            l = l * alpha + p;
            #pragma unroll
            for (int e = 0; e < 16; ++e) o[e] = o[e] * alpha + p * vp[e];
            mx = mn;
        } else {
            float p = __expf(sc - mx);
            l += p;
            #pragma unroll
            for (int e = 0; e < 16; ++e) o[e] += p * vp[e];
        }
        kp += 16; vp += 16;
    }
    float rl = 1.0f / l;
    if (tid < S) {
        size_t base = ((size_t)n * S + tid) * 64 + h * 16;
        #pragma unroll
        for (int e4 = 0; e4 < 4; ++e4) {
            float4 xv = *(const float4*)(x + base + e4 * 4);
            float4 ov;
            ov.x = xv.x + o[e4 * 4 + 0] * rl;
            ov.y = xv.y + o[e4 * 4 + 1] * rl;
            ov.z = xv.z + o[e4 * 4 + 2] * rl;
            ov.w = xv.w + o[e4 * 4 + 3] * rl;
            *(float4*)(hout + base + e4 * 4) = ov;
        }
    }
}

// ---------- LN2 + GEMM [rows,64]@[64,256] + bias + GELU -> mid ----------
__global__ __launch_bounds__(256) void k_mlp1(
    const float* __restrict__ hbuf, const float* __restrict__ g, const float* __restrict__ bta,
    const float* __restrict__ W1, const float* __restrict__ b1,
    float* __restrict__ mid)
{
    __shared__ float As[64 * 68];
    __shared__ float Bs[64 * 64];
    int tid = threadIdx.x;
    int tx = tid & 15, ty = tid >> 4;
    int m0 = blockIdx.y * 64;
    int nc = blockIdx.x;   // 0..3
    int r = tid >> 2, cpart = (tid & 3) * 16;
    {
        const float* hp = hbuf + ((size_t)(m0 + r)) * 64 + cpart;
        float4 hv[4];
        #pragma unroll
        for (int i = 0; i < 4; ++i) hv[i] = *(const float4*)(hp + i * 4);
        float ps = 0.f;
        #pragma unroll
        for (int i = 0; i < 4; ++i) ps += hv[i].x + hv[i].y + hv[i].z + hv[i].w;
        ps += __shfl_xor(ps, 1); ps += __shfl_xor(ps, 2);
        float mean = ps * (1.0f / 64.0f);
        float vs = 0.f;
        #pragma unroll
        for (int i = 0; i < 4; ++i) {
            float dx = hv[i].x - mean, dy = hv[i].y - mean, dz = hv[i].z - mean, dw = hv[i].w - mean;
            vs += dx * dx + dy * dy + dz * dz + dw * dw;
        }
        vs += __shfl_xor(vs, 1); vs += __shfl_xor(vs, 2);
        float rstd = rsqrtf(vs * (1.0f / 64.0f) + EPS);
        #pragma unroll
        for (int i = 0; i < 4; ++i) {
            float4 gv = *(const float4*)(g + cpart + i * 4);
            float4 bv = *(const float4*)(bta + cpart + i * 4);
            float4 zv;
            zv.x = (hv[i].x - mean) * rstd * gv.x + bv.x;
            zv.y = (hv[i].y - mean) * rstd * gv.y + bv.y;
            zv.z = (hv[i].z - mean) * rstd * gv.z + bv.z;
            zv.w = (hv[i].w - mean) * rstd * gv.w + bv.w;
            *(float4*)&As[r * 68 + cpart + i * 4] = zv;
        }
        const float* wp = W1 + (size_t)r * 256 + nc * 64 + cpart;
        #pragma unroll
        for (int i = 0; i < 4; ++i)
            *(float4*)&Bs[r * 64 + cpart + i * 4] = *(const float4*)(wp + i * 4);
    }
    __syncthreads();
    float4 acc[4];
    #pragma unroll
    for (int i = 0; i < 4; ++i) acc[i] = make_float4(0.f, 0.f, 0.f, 0.f);
    #pragma unroll
    for (int k4 = 0; k4 < 16; ++k4) {
        float4 a[4], b[4];
        #pragma unroll
        for (int i = 0; i < 4; ++i) a[i] = *(float4*)&As[(ty + 16 * i) * 68 + k4 * 4];
        #pragma unroll
        for (int kk = 0; kk < 4; ++kk) b[kk] = *(float4*)&Bs[(k4 * 4 + kk) * 64 + tx * 4];
        #pragma unroll
        for (int i = 0; i < 4; ++i) {
            fma4(acc[i], a[i].x, b[0]);
            fma4(acc[i], a[i].y, b[1]);
            fma4(acc[i], a[i].z, b[2]);
            fma4(acc[i], a[i].w, b[3]);
        }
    }
    int col = nc * 64 + tx * 4;
    float4 b1v = *(const float4*)(b1 + col);
    #pragma unroll
    for (int i = 0; i < 4; ++i) {
        int row = m0 + ty + 16 * i;
        float4 ov;
        ov.x = gelu_f(acc[i].x + b1v.x);
        ov.y = gelu_f(acc[i].y + b1v.y);
        ov.z = gelu_f(acc[i].z + b1v.z);
        ov.w = gelu_f(acc[i].w + b1v.w);
        *(float4*)&mid[(size_t)row * 256 + col] = ov;
    }
}

// ---------- GEMM [rows,256]@[256,64] + bias + residual -> out ----------
__global__ __launch_bounds__(256) void k_mlp2(
    const float* __restrict__ mid, const float* __restrict__ W2, const float* __restrict__ b2,
    const float* __restrict__ hbuf, float* __restrict__ out)
{
    __shared__ float As[64 * 68];
    __shared__ float Bs[64 * 64];
    int tid = threadIdx.x;
    int tx = tid & 15, ty = tid >> 4;
    int m0 = blockIdx.x * 64;
    int r = tid >> 2, cpart = (tid & 3) * 16;
    float4 acc[4];
    #pragma unroll
    for (int i = 0; i < 4; ++i) acc[i] = make_float4(0.f, 0.f, 0.f, 0.f);
    for (int kc = 0; kc < 4; ++kc) {
        const float* mp = mid + ((size_t)(m0 + r)) * 256 + kc * 64 + cpart;
        float4 av[4];
        #pragma unroll
        for (int i = 0; i < 4; ++i) av[i] = *(const float4*)(mp + i * 4);
        const float* wp = W2 + (size_t)(kc * 64 + r) * 64 + cpart;
        float4 wv4[4];
        #pragma unroll
        for (int i = 0; i < 4; ++i) wv4[i] = *(const float4*)(wp + i * 4);
        __syncthreads();
        #pragma unroll
        for (int i = 0; i < 4; ++i) {
            *(float4*)&As[r * 68 + cpart + i * 4] = av[i];
            *(float4*)&Bs[r * 64 + cpart + i * 4] = wv4[i];
        }
        __syncthreads();
        #pragma unroll
        for (int k4 = 0; k4 < 16; ++k4) {
            float4 a[4], b[4];
            #pragma unroll
            for (int i = 0; i < 4; ++i) a[i] = *(float4*)&As[(ty + 16 * i) * 68 + k4 * 4];
            #pragma unroll
            for (int kk = 0; kk < 4; ++kk) b[kk] = *(float4*)&Bs[(k4 * 4 + kk) * 64 + tx * 4];
            #pragma unroll
            for (int i = 0; i < 4; ++i) {
                fma4(acc[i], a[i].x, b[0]);
                fma4(acc[i], a[i].y, b[1]);
                fma4(acc[i], a[i].z, b[2]);
                fma4(acc[i], a[i].w, b[3]);
            }
        }
    }
    int col = tx * 4;
    float4 b2v = *(const float4*)(b2 + col);
    #pragma unroll
    for (int i = 0; i < 4; ++i) {
        int row = m0 + ty + 16 * i;
        float4 hv = *(const float4*)(hbuf + (size_t)row * 64 + col);
        float4 ov;
        ov.x = acc[i].x + b2v.x + hv.x;
        ov.y = acc[i].y + b2v.y + hv.y;
        ov.z = acc[i].z + b2v.z + hv.z;
        ov.w = acc[i].w + b2v.w + hv.w;
        *(float4*)&out[(size_t)row * 64 + col] = ov;
    }
}

// ---------- bottleneck: lat = gelu(x[:,1:]@m1W+m1b); xdec = gelu(lat*m4W+m4b) ----------
__global__ __launch_bounds__(256) void k_bneck(
    const float* __restrict__ xenc, const float* __restrict__ m1W, const float* __restrict__ m1b,
    const float* __restrict__ m4W, const float* __restrict__ m4b,
    float* __restrict__ lat_out, float* __restrict__ xdec)
{
    int tid = threadIdx.x, w = tid >> 6, l = tid & 63;
    int row = blockIdx.x * 4 + w;
    if (row >= 128 * 196) return;
    int n = row / 196, p = row - n * 196;
    float xv = xenc[((size_t)(n * 197 + 1 + p)) * 64 + l];
    float sum = wave_sum(xv * m1W[l]);
    float lat = gelu_f(sum + m1b[0]);
    if (l == 0) lat_out[row] = lat;
    float ov = gelu_f(lat * m4W[l] + m4b[l]);
    xdec[(size_t)row * 64 + l] = ov;
}

// ---------- final: img = depatchify((x + pe196) @ lm2_W + lm2_b) ----------
__global__ __launch_bounds__(256) void k_final(
    const float* __restrict__ xdec, const float* __restrict__ pe,
    const float* __restrict__ W, const float* __restrict__ bias,
    float* __restrict__ img_out)
{
    __shared__ float As[64 * 68];
    __shared__ float Bs[64 * 64];
    int tid = threadIdx.x;
    int tx = tid & 15, ty = tid >> 4;
    int m0 = blockIdx.y * 64;
    int nb = blockIdx.x;   // 0..15
    int r = tid >> 2, cpart = (tid & 3) * 16;
    {
        int row = m0 + r;
        int n = row / 196, p = row - n * 196;
        const float* xp = xdec + (size_t)row * 64 + cpart;
        const float* pp = pe + (size_t)p * 64 + cpart;
        #pragma unroll
        for (int i = 0; i < 4; ++i) {
            float4 xv = *(const float4*)(xp + i * 4);
            float4 pv = *(const float4*)(pp + i * 4);
            float4 zv;
            zv.x = xv.x + pv.x; zv.y = xv.y + pv.y; zv.z = xv.z + pv.z; zv.w = xv.w + pv.w;
            *(float4*)&As[r * 68 + cpart + i * 4] = zv;
        }
        const float* wp = W + (size_t)r * 1024 + nb * 64 + cpart;
        #pragma unroll
        for (int i = 0; i < 4; ++i)
            *(float4*)&Bs[r * 64 + cpart + i * 4] = *(const float4*)(wp + i * 4);
    }
    __syncthreads();
    float4 acc[4];
    #pragma unroll
    for (int i = 0; i < 4; ++i) acc[i] = make_float4(0.f, 0.f, 0.f, 0.f);
    #pragma unroll
    for (int k4 = 0; k4 < 16; ++k4) {
        float4 a[4], b[4];
        #pragma unroll
        for (int i = 0; i < 4; ++i) a[i] = *(float4*)&As[(ty + 16 * i) * 68 + k4 * 4];
        #pragma unroll
        for (int kk = 0; kk < 4; ++kk) b[kk] = *(float4*)&Bs[(k4 * 4 + kk) * 64 + tx * 4];
        #pragma unroll
        for (int i = 0; i < 4; ++i) {
            fma4(acc[i], a[i].x, b[0]);
            fma4(acc[i], a[i].y, b[1]);
            fma4(acc[i], a[i].z, b[2]);
            fma4(acc[i], a[i].w, b[3]);
        }
    }
    int colj = nb * 64 + tx * 4;
    float4 bv = *(const float4*)(bias + colj);
    int rr = colj >> 5, cc = colj & 31;
    #pragma unroll
    for (int i = 0; i < 4; ++i) {
        int row = m0 + ty + 16 * i;
        int n = row / 196, p = row - n * 196;
        int pi = p / 14, pj = p - pi * 14;
        size_t off = (size_t)n * 200704 + (size_t)(pi * 32 + rr) * 448 + pj * 32 + cc;
        float4 ov;
        ov.x = acc[i].x + bv.x;
        ov.y = acc[i].y + bv.y;
        ov.z = acc[i].z + bv.z;
        ov.w = acc[i].w + bv.w;
        *(float4*)&img_out[off] = ov;
    }
}

// ---------- host launch ----------
extern "C" void kernel_launch(void* const* d_in, const int* in_sizes, int n_in,
                              void* d_out, int out_size, void* d_ws, size_t ws_size,
                              hipStream_t stream) {
    const float* images = (const float*)d_in[0];
    const float* cls    = (const float*)d_in[1];
    const float* lm_W   = (const float*)d_in[2];
    const float* lm_b   = (const float*)d_in[3];
    const float* lm2_W  = (const float*)d_in[4];
    const float* lm2_b  = (const float*)d_in[5];
    const float* m1W    = (const float*)d_in[6];
    const float* m1b    = (const float*)d_in[7];
    const float* m4W    = (const float*)d_in[8];
    const float* m4b    = (const float*)d_in[9];

    float* pe   = (float*)d_ws;
    float* xb   = pe + 12608;          // 128*197*64
    float* hb   = xb + 1614848;
    float* qb   = hb + 1614848;
    float* kb   = qb + 1614848;
    float* vb   = kb + 1614848;
    float* midb = vb + 1614848;        // 25216*256

    float* lat_out = (float*)d_out;            // 128*196 floats
    float* img_out = (float*)d_out + 25088;    // 128*448*448 floats

    hipLaunchKernelGGL(k_posemb, dim3(50), dim3(256), 0, stream, pe);
    hipLaunchKernelGGL(k_patch, dim3(392), dim3(256), 0, stream, images, lm_W, lm_b, pe, xb);
    hipLaunchKernelGGL(k_cls, dim3(32), dim3(256), 0, stream, cls, pe, xb);

    float* cur_x = xb;
    float* cur_h = hb;
    for (int grp = 0; grp < 2; ++grp) {
        int base = 10 + grp * 14;
        const float* ln1_g = (const float*)d_in[base + 0];
        const float* ln1_b = (const float*)d_in[base + 1];
        const float* ln2_g = (const float*)d_in[base + 2];
        const float* ln2_b = (const float*)d_in[base + 3];
        const float* Wq = (const float*)d_in[base + 4];
        const float* Wk = (const float*)d_in[base + 5];
        const float* Wv = (const float*)d_in[base + 6];
        const float* bq = (const float*)d_in[base + 7];
        const float* bk = (const float*)d_in[base + 8];
        const float* bv = (const float*)d_in[base + 9];
        const float* W1 = (const float*)d_in[base + 10];
        const float* b1 = (const float*)d_in[base + 11];
        const float* W2 = (const float*)d_in[base + 12];
        const float* b2 = (const float*)d_in[base + 13];
        int S = (grp == 0) ? 197 : 196;
        int rows = 128 * S;
        for (int i = 0; i < 2; ++i) {
            hipLaunchKernelGGL(k_ln_qkv, dim3(rows / 4), dim3(256), 0, stream,
                cur_x, ln1_g + i * 64, ln1_b + i * 64,
                Wq + i * 1024, bq + i * 64, Wk + i * 1024, bk + i * 64,
                Wv + i * 1024, bv + i * 64, qb, kb, vb, S);
            hipLaunchKernelGGL(k_attn, dim3(512), dim3(256), 0, stream,
                qb, kb, vb, cur_x, cur_h, S);
            hipLaunchKernelGGL(k_mlp1, dim3(4, rows / 64), dim3(256), 0, stream,
                cur_h, ln2_g + i * 64, ln2_b + i * 64, W1 + i * 16384, b1 + i * 256, midb);
            hipLaunchKernelGGL(k_mlp2, dim3(rows / 64), dim3(256), 0, stream,
                midb, W2 + i * 16384, b2 + i * 64, cur_h, cur_x);
        }
        if (grp == 0) {
            hipLaunchKernelGGL(k_bneck, dim3(6272), dim3(256), 0, stream,
                cur_x, m1W, m1b, m4W, m4b, lat_out, hb);
            cur_x = hb;
            cur_h = xb;
        }
    }
    hipLaunchKernelGGL(k_final, dim3(16, 392), dim3(256), 0, stream, cur_x, pe, lm2_W, lm2_b, img_out);
}